// Round 2
// baseline (218.941 us; speedup 1.0000x reference)
//
#include <hip/hip_runtime.h>
#include <hip/hip_bf16.h>

// Fused: QKV proj (+bias) -> RoPE(Q,K) -> MHA softmax -> out proj (+bias)
// B=8 S=1024 D=1024 H=16 Dk=64.  All GEMMs in bf16 MFMA (16x16x32), fp32 accum.

typedef __bf16 bf16_t;
typedef __bf16 bf16x8 __attribute__((ext_vector_type(8)));
typedef float  f32x4  __attribute__((ext_vector_type(4)));

static __device__ __forceinline__ f32x4 mfma16(bf16x8 a, bf16x8 b, f32x4 c) {
  return __builtin_amdgcn_mfma_f32_16x16x32_bf16(a, b, c, 0, 0, 0);
}
static __device__ __forceinline__ void gload_lds16(const void* g, void* l) {
  __builtin_amdgcn_global_load_lds((const __attribute__((address_space(1))) void*)g,
                                   (__attribute__((address_space(3))) void*)l,
                                   16, 0, 0);
}
#define VMCNT0() asm volatile("s_waitcnt vmcnt(0)" ::: "memory")

// ---------------- prep: fp32 -> bf16 cast (vectorized) ----------------
__global__ void k_cast(const float* __restrict__ s, bf16_t* __restrict__ d, int n4) {
  int i = blockIdx.x * 256 + threadIdx.x;
  if (i >= n4) return;
  float4 v = reinterpret_cast<const float4*>(s)[i];
  union { bf16_t b[4]; unsigned long long u; } pk;
  pk.b[0] = (bf16_t)v.x; pk.b[1] = (bf16_t)v.y;
  pk.b[2] = (bf16_t)v.z; pk.b[3] = (bf16_t)v.w;
  reinterpret_cast<unsigned long long*>(d)[i] = pk.u;
}

// ---------------- prep: rope table rt[s][f] = (cos, sin), f in [0,32) ----
__global__ void k_rope_table(const int* __restrict__ pos, float2* __restrict__ rt) {
  int s = blockIdx.x * 8 + (threadIdx.x >> 5);
  int f = threadIdx.x & 31;
  float p = (float)pos[s];
  float inv = powf(10000.0f, -(float)(2 * f) / 64.0f);
  float a = p * inv;
  rt[s * 32 + f] = make_float2(cosf(a), sinf(a));
}

// ---------------- fused QKV GEMM (m97 structure) ----------------
// C[i,e] = sum_d X[i,d] * W[e,d] + bias[e];  i = b*1024+s, e = h*64+dk
// z=0 -> rope+0.125 -> Qh[b,h,s,dk]; z=1 -> rope -> Kh[b,h,s,dk]; z=2 -> Vt[b,h,dk,s]
__global__ __launch_bounds__(256) void k_gemm_qkv(
    const bf16_t* __restrict__ Xb,
    const bf16_t* __restrict__ Wqb, const bf16_t* __restrict__ Wkb, const bf16_t* __restrict__ Wvb,
    const float* __restrict__ bq, const float* __restrict__ bk, const float* __restrict__ bv,
    const float2* __restrict__ rt,
    bf16_t* __restrict__ Qh, bf16_t* __restrict__ Kh, bf16_t* __restrict__ Vt) {
  __shared__ alignas(16) bf16_t As[2][128][32];
  __shared__ alignas(16) bf16_t Bs[2][128][32];
  const int tid = threadIdx.x;
  const int lane = tid & 63, w = tid >> 6;
  const int hi = lane >> 4, c = lane & 15;
  const int wm = (w >> 1) * 64, wn = (w & 1) * 64;
  const int i0 = blockIdx.x * 128;
  const int e0 = blockIdx.y * 128;
  const int z = blockIdx.z;
  const bf16_t* W = (z == 0) ? Wqb : (z == 1) ? Wkb : Wvb;
  const float* bias = (z == 0) ? bq : (z == 1) ? bk : bv;

  f32x4 acc[4][4] = {};

  const int srow = tid >> 2;      // 0..63 (64B rows, 4 lanes/row)
  const int scg = tid & 3;
  const bf16_t* Ag = Xb + (size_t)(i0 + srow) * 1024 + scg * 8;
  const bf16_t* Bg = W + (size_t)(e0 + srow) * 1024 + scg * 8;

  auto stage = [&](int bi, int k0) {
    char* a_dst = (char*)&As[bi][0][0] + tid * 16;
    char* b_dst = (char*)&Bs[bi][0][0] + tid * 16;
    gload_lds16(Ag + k0, a_dst);
    gload_lds16(Ag + k0 + 64 * 1024, a_dst + 4096);
    gload_lds16(Bg + k0, b_dst);
    gload_lds16(Bg + k0 + 64 * 1024, b_dst + 4096);
  };

  stage(0, 0);
  VMCNT0();
  __syncthreads();
  int buf = 0;
  for (int kt = 0; kt < 32; ++kt) {
    if (kt + 1 < 32) stage(buf ^ 1, (kt + 1) * 32);
    bf16x8 a[4], b[4];
#pragma unroll
    for (int mi = 0; mi < 4; ++mi)
      a[mi] = *(const bf16x8*)&As[buf][wm + mi * 16 + c][hi * 8];
#pragma unroll
    for (int ni = 0; ni < 4; ++ni)
      b[ni] = *(const bf16x8*)&Bs[buf][wn + ni * 16 + c][hi * 8];
#pragma unroll
    for (int mi = 0; mi < 4; ++mi)
#pragma unroll
      for (int ni = 0; ni < 4; ++ni)
        acc[mi][ni] = mfma16(a[mi], b[ni], acc[mi][ni]);
    VMCNT0();
    __syncthreads();
    buf ^= 1;
  }

  // Epilogue. C/D frag: col = c (N=e), rows = hi*4 + r (M=i).
  if (z == 2) {
#pragma unroll
    for (int mi = 0; mi < 4; ++mi) {
      int i = i0 + wm + mi * 16 + hi * 4;
      int b_ = i >> 10, s = i & 1023;
#pragma unroll
      for (int ni = 0; ni < 4; ++ni) {
        int e = e0 + wn + ni * 16 + c;
        int h = e >> 6, dk = e & 63;
        float bv_ = bias[e];
        union { bf16_t b[4]; unsigned long long u; } pk;
#pragma unroll
        for (int r = 0; r < 4; ++r) pk.b[r] = (bf16_t)(acc[mi][ni][r] + bv_);
        // Vt[b,h,dk,s..s+3]  (consecutive regs = consecutive s -> 8B store)
        __builtin_memcpy(&Vt[((size_t)((b_ * 16 + h) * 64 + dk)) * 1024 + s], pk.b, 8);
      }
    }
  } else {
    bf16_t* O = (z == 0) ? Qh : Kh;
    const float scl = (z == 0) ? 0.125f : 1.0f;  // fold 1/sqrt(Dk) into Q
#pragma unroll
    for (int mi = 0; mi < 4; ++mi) {
      int i = i0 + wm + mi * 16 + hi * 4;
      int b_ = i >> 10, sbase = i & 1023;
#pragma unroll
      for (int ni = 0; ni < 2; ++ni) {  // dk in [0,32); partner dk+32 is frag ni+2
        int e1 = e0 + wn + ni * 16 + c;
        int h = e1 >> 6, f = e1 & 63;  // f < 32
        float b1 = bias[e1], b2 = bias[e1 + 32];
        size_t obase = (size_t)((b_ * 16 + h) * 1024);
#pragma unroll
        for (int r = 0; r < 4; ++r) {
          int s = sbase + r;
          float2 cs = rt[s * 32 + f];
          float q1 = acc[mi][ni][r] + b1;
          float q2 = acc[mi][ni + 2][r] + b2;
          O[(obase + s) * 64 + f] = (bf16_t)((q1 * cs.x - q2 * cs.y) * scl);
          O[(obase + s) * 64 + f + 32] = (bf16_t)((q1 * cs.y + q2 * cs.x) * scl);
        }
      }
    }
  }
}

// ---------------- flash attention ----------------
// grid (16 qtiles, 128 bh), block 256 (4 waves x 16 q-rows).
// Swapped QK^T: ST[k][q] = mfma(A=K, B=Q^T) so softmax stats are per-lane (q = c).
__global__ __launch_bounds__(256) void k_attn(
    const bf16_t* __restrict__ Qh, const bf16_t* __restrict__ Kh,
    const bf16_t* __restrict__ Vt, bf16_t* __restrict__ Og) {
  __shared__ alignas(16) bf16_t Ks[2][64][64];
  __shared__ alignas(16) bf16_t Vs[2][64][64];
  __shared__ alignas(16) bf16_t Pl[4][16][72];  // +8 pad breaks bank conflicts
  const int tid = threadIdx.x;
  const int lane = tid & 63, w = tid >> 6;
  const int hi = lane >> 4, c = lane & 15;
  const int bh = blockIdx.y;
  const int q0 = blockIdx.x * 64 + w * 16;
  const size_t base = (size_t)bh * 64 * 1024;

  // Q as B-fragment: lane holds Q[q0+c][kk*32 + hi*8 .. +8]
  bf16x8 qf[2];
  qf[0] = *(const bf16x8*)&Qh[base + (size_t)(q0 + c) * 64 + hi * 8];
  qf[1] = *(const bf16x8*)&Qh[base + (size_t)(q0 + c) * 64 + 32 + hi * 8];

  f32x4 o[4] = {};
  float m = -1e30f, lsum = 0.f;

  const int srow = tid >> 3;  // 0..31 ; 128B rows, 8 lanes/row
  const int scg = tid & 7;
  const int sxor = srow & 7;  // pre-swizzle source so LDS stays linear (m173)
  auto stageK = [&](int bi, int k0) {
    char* dst = (char*)&Ks[bi][0][0] + tid * 16;
    gload_lds16(&Kh[base + (size_t)(k0 + srow) * 64 + ((scg ^ sxor) * 8)], dst);
    gload_lds16(&Kh[base + (size_t)(k0 + srow + 32) * 64 + ((scg ^ sxor) * 8)], dst + 4096);
  };
  auto stageV = [&](int bi, int k0) {
    char* dst = (char*)&Vs[bi][0][0] + tid * 16;
    gload_lds16(&Vt[base + (size_t)srow * 1024 + k0 + ((scg ^ sxor) * 8)], dst);
    gload_lds16(&Vt[base + (size_t)(srow + 32) * 1024 + k0 + ((scg ^ sxor) * 8)], dst + 4096);
  };

  stageK(0, 0);
  stageV(0, 0);
  VMCNT0();
  __syncthreads();
  int buf = 0;
  for (int t = 0; t < 16; ++t) {
    if (t + 1 < 16) { stageK(buf ^ 1, (t + 1) * 64); stageV(buf ^ 1, (t + 1) * 64); }
    // ST[k][q]: A-frag = K rows (XOR-swizzled read matches pre-swizzled stage)
    f32x4 st[4] = {};
#pragma unroll
    for (int ni = 0; ni < 4; ++ni) {
#pragma unroll
      for (int kk = 0; kk < 2; ++kk) {
        int row = ni * 16 + c;
        int cg = kk * 4 + hi;
        bf16x8 kf = *(const bf16x8*)((const char*)&Ks[buf][0][0] + row * 128 +
                                     ((cg ^ (row & 7)) * 16));
        st[ni] = mfma16(kf, qf[kk], st[ni]);
      }
    }
    // online softmax: lane holds k = ni*16 + hi*4 + r for q-column c
    float pmax = -1e30f;
#pragma unroll
    for (int ni = 0; ni < 4; ++ni)
#pragma unroll
      for (int r = 0; r < 4; ++r) pmax = fmaxf(pmax, st[ni][r]);
    pmax = fmaxf(pmax, __shfl_xor(pmax, 16));
    pmax = fmaxf(pmax, __shfl_xor(pmax, 32));
    float mn = fmaxf(m, pmax);
    float scale = __expf(m - mn);
    m = mn;
    float psum = 0.f;
#pragma unroll
    for (int ni = 0; ni < 4; ++ni) {
      union { bf16_t b[4]; unsigned long long u; } pk;
#pragma unroll
      for (int r = 0; r < 4; ++r) {
        float p = __expf(st[ni][r] - mn);
        psum += p;
        pk.b[r] = (bf16_t)p;
      }
      __builtin_memcpy(&Pl[w][c][ni * 16 + hi * 4], pk.b, 8);  // P[q][k], 4 consec k
    }
    psum += __shfl_xor(psum, 16);
    psum += __shfl_xor(psum, 32);
    lsum = lsum * scale + psum;
    // rescale O: O-frag row q = hi*4 + r ; stats live at lane (q) [q<16]
#pragma unroll
    for (int r = 0; r < 4; ++r) {
      float sr = __shfl(scale, hi * 4 + r);
#pragma unroll
      for (int od = 0; od < 4; ++od) o[od][r] *= sr;
    }
    // PV: A = P from wave-private LDS, B = V (Vt rows contiguous in k)
    bf16x8 pa[2];
    __builtin_memcpy(&pa[0], &Pl[w][c][hi * 8], 16);
    __builtin_memcpy(&pa[1], &Pl[w][c][32 + hi * 8], 16);
#pragma unroll
    for (int od = 0; od < 4; ++od) {
#pragma unroll
      for (int kk = 0; kk < 2; ++kk) {
        int row = od * 16 + c;
        int cg = kk * 4 + hi;
        bf16x8 vf = *(const bf16x8*)((const char*)&Vs[buf][0][0] + row * 128 +
                                     ((cg ^ (row & 7)) * 16));
        o[od] = mfma16(pa[kk], vf, o[od]);
      }
    }
    VMCNT0();
    __syncthreads();
    buf ^= 1;
  }

  float invl = 1.0f / lsum;
  int b_ = bh >> 4, h = bh & 15;
#pragma unroll
  for (int r = 0; r < 4; ++r) {
    float ir = __shfl(invl, hi * 4 + r);
    int s = q0 + hi * 4 + r;
    size_t rowoff = ((size_t)(b_ * 1024 + s)) * 1024 + h * 64;
#pragma unroll
    for (int od = 0; od < 4; ++od)
      Og[rowoff + od * 16 + c] = (bf16_t)(o[od][r] * ir);
  }
}

// ---------------- out projection ----------------
__global__ __launch_bounds__(256) void k_gemm_out(
    const bf16_t* __restrict__ Og, const bf16_t* __restrict__ Wob,
    const float* __restrict__ bo, float* __restrict__ out) {
  __shared__ alignas(16) bf16_t As[2][128][32];
  __shared__ alignas(16) bf16_t Bs[2][128][32];
  const int tid = threadIdx.x;
  const int lane = tid & 63, w = tid >> 6;
  const int hi = lane >> 4, c = lane & 15;
  const int wm = (w >> 1) * 64, wn = (w & 1) * 64;
  const int i0 = blockIdx.x * 128;
  const int e0 = blockIdx.y * 128;

  f32x4 acc[4][4] = {};
  const int srow = tid >> 2;
  const int scg = tid & 3;
  const bf16_t* Ag = Og + (size_t)(i0 + srow) * 1024 + scg * 8;
  const bf16_t* Bg = Wob + (size_t)(e0 + srow) * 1024 + scg * 8;

  auto stage = [&](int bi, int k0) {
    char* a_dst = (char*)&As[bi][0][0] + tid * 16;
    char* b_dst = (char*)&Bs[bi][0][0] + tid * 16;
    gload_lds16(Ag + k0, a_dst);
    gload_lds16(Ag + k0 + 64 * 1024, a_dst + 4096);
    gload_lds16(Bg + k0, b_dst);
    gload_lds16(Bg + k0 + 64 * 1024, b_dst + 4096);
  };

  stage(0, 0);
  VMCNT0();
  __syncthreads();
  int buf = 0;
  for (int kt = 0; kt < 32; ++kt) {
    if (kt + 1 < 32) stage(buf ^ 1, (kt + 1) * 32);
    bf16x8 a[4], b[4];
#pragma unroll
    for (int mi = 0; mi < 4; ++mi)
      a[mi] = *(const bf16x8*)&As[buf][wm + mi * 16 + c][hi * 8];
#pragma unroll
    for (int ni = 0; ni < 4; ++ni)
      b[ni] = *(const bf16x8*)&Bs[buf][wn + ni * 16 + c][hi * 8];
#pragma unroll
    for (int mi = 0; mi < 4; ++mi)
#pragma unroll
      for (int ni = 0; ni < 4; ++ni)
        acc[mi][ni] = mfma16(a[mi], b[ni], acc[mi][ni]);
    VMCNT0();
    __syncthreads();
    buf ^= 1;
  }

#pragma unroll
  for (int mi = 0; mi < 4; ++mi) {
    int i = i0 + wm + mi * 16 + hi * 4;
#pragma unroll
    for (int ni = 0; ni < 4; ++ni) {
      int e = e0 + wn + ni * 16 + c;
      float bv_ = bo[e];
#pragma unroll
      for (int r = 0; r < 4; ++r)
        out[(size_t)(i + r) * 1024 + e] = acc[mi][ni][r] + bv_;
    }
  }
}

extern "C" void kernel_launch(void* const* d_in, const int* in_sizes, int n_in,
                              void* d_out, int out_size, void* d_ws, size_t ws_size,
                              hipStream_t stream) {
  const float* x = (const float*)d_in[0];
  const int* pos = (const int*)d_in[1];
  const float* Wq = (const float*)d_in[2];
  const float* bq = (const float*)d_in[3];
  const float* Wk = (const float*)d_in[4];
  const float* bk = (const float*)d_in[5];
  const float* Wv = (const float*)d_in[6];
  const float* bv = (const float*)d_in[7];
  const float* Wo = (const float*)d_in[8];
  const float* bo = (const float*)d_in[9];
  float* out = (float*)d_out;

  // Workspace layout (bytes):
  //   [0,16M)   Xb (bf16 x)   -- reused as Og after QKV GEMM
  //   [16M,24M) Wq/Wk/Wv/Wo bf16 (2MB each)
  //   [24M,40M) Vt bf16 [B,H,64,S]
  //   [42M,..)  rope table float2[1024][32]
  // Q,K (bf16, 16MB each) live in d_out (32MB) -- dead before out-proj writes it.
  char* ws = (char*)d_ws;
  bf16_t* Xb = (bf16_t*)ws;
  bf16_t* Wqb = (bf16_t*)(ws + (16u << 20));
  bf16_t* Wkb = (bf16_t*)(ws + (18u << 20));
  bf16_t* Wvb = (bf16_t*)(ws + (20u << 20));
  bf16_t* Wob = (bf16_t*)(ws + (22u << 20));
  bf16_t* Vt = (bf16_t*)(ws + (24u << 20));
  float2* rt = (float2*)(ws + (42u << 20));
  bf16_t* Qh = (bf16_t*)d_out;
  bf16_t* Kh = (bf16_t*)d_out + (size_t)8 * 1024 * 1024;
  bf16_t* Og = Xb;

  k_cast<<<8192, 256, 0, stream>>>(x, Xb, 8192 * 1024 / 4);
  k_cast<<<1024, 256, 0, stream>>>(Wq, Wqb, 1024 * 1024 / 4);
  k_cast<<<1024, 256, 0, stream>>>(Wk, Wkb, 1024 * 1024 / 4);
  k_cast<<<1024, 256, 0, stream>>>(Wv, Wvb, 1024 * 1024 / 4);
  k_cast<<<1024, 256, 0, stream>>>(Wo, Wob, 1024 * 1024 / 4);
  k_rope_table<<<128, 256, 0, stream>>>(pos, rt);

  k_gemm_qkv<<<dim3(64, 8, 3), 256, 0, stream>>>(Xb, Wqb, Wkb, Wvb, bq, bk, bv, rt,
                                                 Qh, Kh, Vt);
  k_attn<<<dim3(16, 128), 256, 0, stream>>>(Qh, Kh, Vt, Og);
  k_gemm_out<<<dim3(64, 8), 256, 0, stream>>>(Og, Wob, bo, out);
}